// Round 10
// baseline (696.811 us; speedup 1.0000x reference)
//
#include <hip/hip_runtime.h>

// Soft-DTW, gamma=1.0, B=64, N=M=1024, log2-domain DP, barrier-free.
// Column-strip row-sweep: one 256-thread block per batch; thread t owns DP
// columns 4t+1..4t+4 and computes TWO rows per iteration (pair p = rows
// 2p+1, 2p+2). Links = 512 + skew(255+15) = ~782.
// Handoff thread t-1 -> t: DPP row_shr:1 (pure VALU, ~5 cyc) for lanes
// !=0 mod 16; lanes ==0 mod 16 via LDS ring mailbox (tag protocol, preloaded
// one iteration ahead; full 512-slot rings for the 3 inter-wave boundaries,
// 8-slot rings for the 12 lockstep intra-wave boundaries). skew(t)=t+(t>>4).
// Pair representation (u,s), v = u - log2(s); renorm every 4 iters (8 rows).
// D: asm global_load_dwordx4 ring (8 outstanding), s_waitcnt vmcnt(6).
// (R9 fix: no offset:4096 immediate — 13-bit signed max is 4095; second-row
// load uses an explicit addr + N pointer instead.)

#define BIGV 1.0e10f
#define LOG2E 1.4426950408889634f
#define LN2  0.6931471805599453f

constexpr int N = 1024;
constexpr int TPB = 256;
constexpr int KC = 4;                // columns per thread
constexpr int NP = N / 2;            // 512 row-pairs
constexpr int ITER = 784;            // >= 512 + 270, multiple of 4

__device__ __forceinline__ float fexp2(float x){float r;asm("v_exp_f32 %0, %1":"=v"(r):"v"(x));return r;}
__device__ __forceinline__ float flog2(float x){float r;asm("v_log_f32 %0, %1":"=v"(r):"v"(x));return r;}
__device__ __forceinline__ float fmin3(float a,float b,float c){float r;asm("v_min3_f32 %0,%1,%2,%3":"=v"(r):"v"(a),"v"(b),"v"(c));return r;}
__device__ __forceinline__ void gload4(float4& d, const float* p){
    asm volatile("global_load_dwordx4 %0, %1, off" : "=v"(d) : "v"(p));
}
__device__ __forceinline__ float dppshr1(float x){
    return __int_as_float(__builtin_amdgcn_update_dpp(
        __float_as_int(x), __float_as_int(x), 0x111, 0xF, 0xF, false));
}
__device__ __forceinline__ void cellp(float au,float as_,float bu,float bs,
                                      float cu,float cs,float d,
                                      float& ou,float& os){
    float mn = fmin3(au,bu,cu);
    float ea = fexp2(mn-au), eb = fexp2(mn-bu), ec = fexp2(mn-cu);
    os = fmaf(as_,ea, fmaf(bs,eb, cs*ec));
    ou = fmaf(d, LOG2E, mn);
}

__global__ __launch_bounds__(TPB)
void softdtw_kernel(const float* __restrict__ D, float* __restrict__ out){
    const int b = blockIdx.x;
    const int t = threadIdx.x;
    const float* __restrict__ Db = D + (size_t)b * N * N;
    const int skew = t + (t >> 4);

    __shared__ float bigPay[3][512][4];
    __shared__ int   bigTag[3][512];
    __shared__ float smlPay[12][8][4];
    __shared__ int   smlTag[12][8];

    for (int i = t; i < 3 * 512; i += TPB) ((int*)bigTag)[i] = -1;
    if (t < 96) ((int*)smlTag)[t] = -1;
    __syncthreads();   // once, before the pipeline

    const bool isProd = ((t & 15) == 15) && (t != TPB - 1);
    const bool isCons = ((t & 15) == 0) && (t != 0);
    float* payP = nullptr; int* tagP = nullptr; int slotM = 0;
    if (isProd || isCons) {
        int bb = isProd ? (t >> 4) : ((t >> 4) - 1);
        if ((bb & 3) == 3) { payP = &bigPay[bb >> 2][0][0]; tagP = &bigTag[bb >> 2][0]; slotM = 511; }
        else { int si = bb - (bb >> 2); payP = &smlPay[si][0][0]; tagP = &smlTag[si][0]; slotM = 7; }
    }

    float puU[KC], puS[KC];
#pragma unroll
    for (int m = 0; m < KC; ++m) { puU[m] = BIGV; puS[m] = 1.0f; }
    float ex1u = BIGV, ex1s = 1.0f, ex2u = BIGV, ex2s = 1.0f;
    float luU = (t == 0) ? 0.0f : BIGV, luS = 1.0f;
    float ptU1 = BIGV, ptS1 = 1.0f, ptU2 = BIGV, ptS2 = 1.0f;
    int preTag = -2;

    const float* addr = Db + t * KC;   // row 2p, my 4 columns
    float4 ld[4][2];
#pragma unroll
    for (int x = 0; x < 4; ++x) {      // prologue: loads for j=0..3
        gload4(ld[x][0], addr);
        gload4(ld[x][1], addr + N);
        int pn = x + 1 - skew;
        addr += ((unsigned)(pn - 1) < (unsigned)(NP - 1)) ? 2 * N : 0;
    }

    for (int jb = 0; jb < ITER; jb += 4) {
#pragma unroll
        for (int u = 0; u < 4; ++u) {
            const int p = jb + u - skew;

            // ---- handoff: DPP row_shr:1 (all lanes, uniform flow) ----
            float e1u = dppshr1(ex1u), e1s = dppshr1(ex1s);
            float e2u = dppshr1(ex2u), e2s = dppshr1(ex2s);

            // mailbox consume (lanes ==0 mod 16, t>0)
            if (isCons && (unsigned)p < (unsigned)NP) {
                if (preTag != p) {                       // slow path (inter-wave drift)
                    volatile int* tp = &tagP[p & slotM];
                    while (*tp != p) { }
                    volatile float* pp = &payP[(p & slotM) * 4];
                    ptU1 = pp[0]; ptS1 = pp[1]; ptU2 = pp[2]; ptS2 = pp[3];
                }
                e1u = ptU1; e1s = ptS1; e2u = ptU2; e2s = ptS2;
            }
            if (t == 0) { e1u = BIGV; e1s = 1.0f; e2u = BIGV; e2s = 1.0f; }

            // preload mailbox for next iteration (tag first, then payload)
            if (isCons && (unsigned)(p + 1) < (unsigned)NP) {
                int sl = (p + 1) & slotM;
                preTag = *(volatile int*)&tagP[sl];
                volatile float* pp = &payP[sl * 4];
                ptU1 = pp[0]; ptS1 = pp[1]; ptU2 = pp[2]; ptS2 = pp[3];
            }

            // ---- D pair landed (issued 4 iterations ago) ----
            asm volatile("s_waitcnt vmcnt(6)" ::: "memory");
            __builtin_amdgcn_sched_barrier(0);
            const float4 dA = ld[u][0];   // row 2p
            const float4 dB = ld[u][1];   // row 2p+1

            // ---- 2x4 tile, anti-diagonal ILP; unconditional (BIG-preserving)
            float r1u[4], r1s[4], r2u[4], r2s[4];
            cellp(luU,luS,     puU[0],puS[0], e1u,e1s,       dA.x, r1u[0],r1s[0]);
            cellp(puU[0],puS[0],puU[1],puS[1], r1u[0],r1s[0], dA.y, r1u[1],r1s[1]);
            cellp(e1u,e1s,     r1u[0],r1s[0], e2u,e2s,       dB.x, r2u[0],r2s[0]);
            cellp(puU[1],puS[1],puU[2],puS[2], r1u[1],r1s[1], dA.z, r1u[2],r1s[2]);
            cellp(r1u[0],r1s[0],r1u[1],r1s[1], r2u[0],r2s[0], dB.y, r2u[1],r2s[1]);
            cellp(puU[2],puS[2],puU[3],puS[3], r1u[2],r1s[2], dA.w, r1u[3],r1s[3]);
            cellp(r1u[1],r1s[1],r1u[2],r1s[2], r2u[1],r2s[1], dB.z, r2u[2],r2s[2]);
            cellp(r1u[2],r1s[2],r1u[3],r1s[3], r2u[2],r2s[2], dB.w, r2u[3],r2s[3]);

#pragma unroll
            for (int m = 0; m < KC; ++m) { puU[m] = r2u[m]; puS[m] = r2s[m]; }
            luU = e2u; luS = e2s;
            ex1u = r1u[3]; ex1s = r1s[3];
            ex2u = r2u[3]; ex2s = r2s[3];

            // ---- mailbox produce (payload then tag; DS in-order per wave)
            if (isProd && (unsigned)p < (unsigned)NP) {
                int sl = p & slotM;
                volatile float* pp = &payP[sl * 4];
                pp[0] = ex1u; pp[1] = ex1s; pp[2] = ex2u; pp[3] = ex2s;
                *(volatile int*)&tagP[sl] = p;
            }

            // ---- issue D loads for iteration j+4 ----
            gload4(ld[u][0], addr);
            gload4(ld[u][1], addr + N);
            {
                int pn = p + 5;
                addr += ((unsigned)(pn - 1) < (unsigned)(NP - 1)) ? 2 * N : 0;
            }

            // ---- renorm every 4 iterations (value-preserving) ----
            if (u == 3) {
#pragma unroll
                for (int m = 0; m < KC; ++m) { puU[m] -= flog2(puS[m]); puS[m] = 1.0f; }
                ex1u -= flog2(ex1s); ex1s = 1.0f;
                ex2u -= flog2(ex2s); ex2s = 1.0f;
                luU  -= flog2(luS);  luS  = 1.0f;
            }
        }
    }

    // R[N][N] = thread 255's pu[3]; unscale from log2 domain
    if (t == TPB - 1) out[b] = (puU[KC - 1] - flog2(puS[KC - 1])) * LN2;
}

extern "C" void kernel_launch(void* const* d_in, const int* in_sizes, int n_in,
                              void* d_out, int out_size, void* d_ws, size_t ws_size,
                              hipStream_t stream) {
    const float* D = (const float*)d_in[0];
    float* out = (float*)d_out;
    const int B = in_sizes[0] / (N * N);
    softdtw_kernel<<<B, TPB, 0, stream>>>(D, out);
}

// Round 11
// 416.576 us; speedup vs baseline: 1.6727x; 1.6727x over previous
//
#include <hip/hip_runtime.h>

// Soft-DTW, gamma=1.0, B=64, N=M=1024, log2-domain DP, barrier-free.
// R11 = R8 skeleton (proven absmax 0.0) + 2 rows/iter + pipelined shfl.
// One 256-thread block per batch; thread t owns DP columns 4t+1..4t+4 and
// computes row-pair p = j - t (rows 2p+1, 2p+2) at iteration j; 768 iters.
// Handoff t-1 -> t: full-wave __shfl_up of the right-edge (u,s) pairs,
// issued at END of iteration j for use at j+1 (latency pipelined).
// Wave boundaries (3): LDS mailbox, groups of 4 pairs (8 rows), seq counter
// with lgkmcnt fence (R8 protocol); consumer polls once per 4 iterations;
// steady-state wave lag ~3 iterations absorbs it.
// Pair representation (u,s), v = u - log2(s); renorm every 4 iters (8 rows).
// State commits masked by `active` (no garbage past a thread's last pair).
// D: asm global_load_dwordx4 ring (8 outstanding), counted vmcnt(6).

#define BIGV 1.0e10f
#define LOG2E 1.4426950408889634f
#define LN2  0.6931471805599453f

constexpr int N = 1024;
constexpr int TPB = 256;
constexpr int KC = 4;                // columns per thread
constexpr int NP = N / 2;            // 512 row-pairs
constexpr int NG = NP / 4;           // 128 groups of 4 pairs (8 rows)
constexpr int ITER = 768;            // last real: 511 + 255 = 766

__device__ __forceinline__ float fexp2(float x){float r;asm("v_exp_f32 %0, %1":"=v"(r):"v"(x));return r;}
__device__ __forceinline__ float flog2(float x){float r;asm("v_log_f32 %0, %1":"=v"(r):"v"(x));return r;}
__device__ __forceinline__ float fmin3(float a,float b,float c){float r;asm("v_min3_f32 %0,%1,%2,%3":"=v"(r):"v"(a),"v"(b),"v"(c));return r;}
__device__ __forceinline__ void gload4(float4& d, const float* p){
    asm volatile("global_load_dwordx4 %0, %1, off" : "=v"(d) : "v"(p));
}
__device__ __forceinline__ void cellp(float au,float as_,float bu,float bs,
                                      float cu,float cs,float d,
                                      float& ou,float& os){
    float mn = fmin3(au,bu,cu);
    float ea = fexp2(mn-au), eb = fexp2(mn-bu), ec = fexp2(mn-cu);
    os = fmaf(as_,ea, fmaf(bs,eb, cs*ec));
    ou = fmaf(d, LOG2E, mn);
}

__global__ __launch_bounds__(TPB)
void softdtw_kernel(const float* __restrict__ D, float* __restrict__ out){
    const int b = blockIdx.x;
    const int t = threadIdx.x;
    const int lane = t & 63;
    const int w = t >> 6;
    const float* __restrict__ bp = D + (size_t)b * N * N + t * KC;

    __shared__ float pay[3][NG][4][4];
    __shared__ int seqv[3];
    if (t < 3) seqv[t] = -1;
    __syncthreads();   // once, before the pipeline

    const bool isProd = (lane == 63) && (w < 3);
    const bool isCons = (lane == 0) && (w > 0);

    float puU[KC], puS[KC];
#pragma unroll
    for (int m = 0; m < KC; ++m) { puU[m] = BIGV; puS[m] = 1.0f; }
    float ex1u = BIGV, ex1s = 1.0f, ex2u = BIGV, ex2s = 1.0f;
    float luU = (t == 0) ? 0.0f : BIGV, luS = 1.0f;
    float n1u = BIGV, n1s = 1.0f, n2u = BIGV, n2s = 1.0f;  // pipelined shfl
    float mb1u[4], mb1s[4], mb2u[4], mb2s[4];
#pragma unroll
    for (int q = 0; q < 4; ++q) { mb1u[q]=BIGV; mb1s[q]=1.0f; mb2u[q]=BIGV; mb2s[q]=1.0f; }

    float4 ld[4][2];
#pragma unroll
    for (int x = 0; x < 4; ++x) {        // prologue loads for j=0..3
        int pc = min(max(x - t, 0), NP - 1);
        const float* a = bp + (size_t)pc * (2 * N);
        gload4(ld[x][0], a);
        gload4(ld[x][1], a + N);
    }

    for (int jb = 0; jb < ITER; jb += 4) {
#pragma unroll
        for (int u = 0; u < 4; ++u) {
            const int p = jb + u - t;
            const bool active = (unsigned)p < (unsigned)NP;

            // mailbox group read (consumers; p%4==0 exactly at u==0 since t%64==0)
            if (u == 0 && isCons && active) {
                const int gq = p >> 2;
                volatile int* sp = &seqv[w - 1];
                int sv; do { sv = *sp; } while (sv < gq);
                asm volatile("s_waitcnt lgkmcnt(0)" ::: "memory");
                const float* pp = &pay[w - 1][gq][0][0];
#pragma unroll
                for (int q = 0; q < 4; ++q) {
                    mb1u[q] = pp[4*q];     mb1s[q] = pp[4*q + 1];
                    mb2u[q] = pp[4*q + 2]; mb2s[q] = pp[4*q + 3];
                }
            }

            float e1u = n1u, e1s = n1s, e2u = n2u, e2s = n2s;
            if (isCons) { e1u = mb1u[u]; e1s = mb1s[u]; e2u = mb2u[u]; e2s = mb2s[u]; }
            if (t == 0) { e1u = BIGV; e1s = 1.0f; e2u = BIGV; e2s = 1.0f; }

            // D pair landed (issued 4 iterations ago)
            asm volatile("s_waitcnt vmcnt(6)" ::: "memory");
            __builtin_amdgcn_sched_barrier(0);
            const float4 dA = ld[u][0];   // row 2p
            const float4 dB = ld[u][1];   // row 2p+1

            // 2x4 tile, anti-diagonal ILP (unconditional compute)
            float r1u[4], r1s[4], r2u[4], r2s[4];
            cellp(luU,luS,       puU[0],puS[0], e1u,e1s,       dA.x, r1u[0],r1s[0]);
            cellp(puU[0],puS[0], puU[1],puS[1], r1u[0],r1s[0], dA.y, r1u[1],r1s[1]);
            cellp(e1u,e1s,       r1u[0],r1s[0], e2u,e2s,       dB.x, r2u[0],r2s[0]);
            cellp(puU[1],puS[1], puU[2],puS[2], r1u[1],r1s[1], dA.z, r1u[2],r1s[2]);
            cellp(r1u[0],r1s[0], r1u[1],r1s[1], r2u[0],r2s[0], dB.y, r2u[1],r2s[1]);
            cellp(puU[2],puS[2], puU[3],puS[3], r1u[2],r1s[2], dA.w, r1u[3],r1s[3]);
            cellp(r1u[1],r1s[1], r1u[2],r1s[2], r2u[1],r2s[1], dB.z, r2u[2],r2s[2]);
            cellp(r1u[2],r1s[2], r1u[3],r1s[3], r2u[2],r2s[2], dB.w, r2u[3],r2s[3]);

            if (active) {                  // masked commit (no garbage writes)
#pragma unroll
                for (int m = 0; m < KC; ++m) { puU[m] = r2u[m]; puS[m] = r2s[m]; }
                luU = e2u; luS = e2s;
                ex1u = r1u[3]; ex1s = r1s[3];
                ex2u = r2u[3]; ex2s = r2s[3];
            }

            // producer: payload each pair; seq bump at group end (p%4==3 <=> u==2)
            if (isProd && active) {
                volatile float* pp = &pay[w][p >> 2][p & 3][0];
                pp[0] = r1u[3]; pp[1] = r1s[3]; pp[2] = r2u[3]; pp[3] = r2s[3];
            }
            if (u == 2 && isProd && active) {
                asm volatile("s_waitcnt lgkmcnt(0)" ::: "memory");
                *(volatile int*)&seqv[w] = (p >> 2);
            }

            // issue D loads for iteration j+4
            {
                int pc = min(max(p + 4, 0), NP - 1);
                const float* a = bp + (size_t)pc * (2 * N);
                gload4(ld[u][0], a);
                gload4(ld[u][1], a + N);
            }

            // renorm every 4 iterations (8 rows; value-preserving)
            if (u == 3) {
#pragma unroll
                for (int m = 0; m < KC; ++m) { puU[m] -= flog2(puS[m]); puS[m] = 1.0f; }
                ex1u -= flog2(ex1s); ex1s = 1.0f;
                ex2u -= flog2(ex2s); ex2s = 1.0f;
                luU  -= flog2(luS);  luS  = 1.0f;
            }

            // pipelined handoff: shfl committed edges for NEXT iteration
            n1u = __shfl_up(ex1u, 1); n1s = __shfl_up(ex1s, 1);
            n2u = __shfl_up(ex2u, 1); n2s = __shfl_up(ex2s, 1);
        }
    }

    // R[N][N] = thread 255's pair-511 bottom-right; renormed at final u==3
    if (t == TPB - 1) out[b] = (puU[KC - 1] - flog2(puS[KC - 1])) * LN2;
}

extern "C" void kernel_launch(void* const* d_in, const int* in_sizes, int n_in,
                              void* d_out, int out_size, void* d_ws, size_t ws_size,
                              hipStream_t stream) {
    const float* D = (const float*)d_in[0];
    float* out = (float*)d_out;
    const int B = in_sizes[0] / (N * N);
    softdtw_kernel<<<B, TPB, 0, stream>>>(D, out);
}

// Round 12
// 367.552 us; speedup vs baseline: 1.8958x; 1.1334x over previous
//
#include <hip/hip_runtime.h>

// Soft-DTW, gamma=1.0, B=64, N=M=1024, log2-domain DP, barrier-free.
// R12 = R11 skeleton (proven absmax 0.0) + ILP restructure:
//  - __launch_bounds__(256,1): unlock VGPRs (R11's VGPR=52 forced a
//    dependence-serialized schedule: measured ~158 cyc/cell ~= 5-7 cyc/instr).
//  - u-pass / exp2-pass / sigma-pass separation: u-recursion (min3+fma) is
//    exp2-free; all 24 exp2s become independent after it; sigma fma-trees last.
//  - normalized single-float edge handoff (v = u - log2 s): 2 shfls not 4,
//    mailbox payload 2 floats, boundary sigma terms constant-fold (s==1).
// Thread t owns DP columns 4t+1..4t+4; computes row-pair p = j - t at
// iteration j (rows 2p+1, 2p+2); 768 iterations. Wave boundaries via LDS
// mailbox (groups of 4 pairs, seq counter + lgkm fence, R8 protocol).
// D: asm global_load_dwordx4 ring (8 outstanding), counted vmcnt(6).

#define BIGV 1.0e10f
#define LOG2E 1.4426950408889634f
#define LN2  0.6931471805599453f

constexpr int N = 1024;
constexpr int TPB = 256;
constexpr int KC = 4;                // columns per thread
constexpr int NP = N / 2;            // 512 row-pairs
constexpr int NG = NP / 4;           // 128 groups of 4 pairs
constexpr int ITER = 768;            // last real iteration: 511 + 255 = 766

__device__ __forceinline__ float fexp2(float x){float r;asm("v_exp_f32 %0, %1":"=v"(r):"v"(x));return r;}
__device__ __forceinline__ float flog2(float x){float r;asm("v_log_f32 %0, %1":"=v"(r):"v"(x));return r;}
__device__ __forceinline__ float fmin3(float a,float b,float c){float r;asm("v_min3_f32 %0,%1,%2,%3":"=v"(r):"v"(a),"v"(b),"v"(c));return r;}
__device__ __forceinline__ void gload4(float4& d, const float* p){
    asm volatile("global_load_dwordx4 %0, %1, off" : "=v"(d) : "v"(p));
}

__global__ __launch_bounds__(TPB, 1)
void softdtw_kernel(const float* __restrict__ D, float* __restrict__ out){
    const int b = blockIdx.x;
    const int t = threadIdx.x;
    const int lane = t & 63;
    const int w = t >> 6;
    const float* __restrict__ bp = D + (size_t)b * N * N + t * KC;

    __shared__ float pay[3][NG][4][2];
    __shared__ int seqv[3];
    if (t < 3) seqv[t] = -1;
    __syncthreads();   // once, before the pipeline

    const bool isProd = (lane == 63) && (w < 3);
    const bool isCons = (lane == 0) && (w > 0);

    float puU[KC], puS[KC];
#pragma unroll
    for (int m = 0; m < KC; ++m) { puU[m] = BIGV; puS[m] = 1.0f; }
    float ex1 = BIGV, ex2 = BIGV;        // my normalized right edges (rows of pair)
    float lu  = (t == 0) ? 0.0f : BIGV;  // up-left corner (normalized)
    float n1 = BIGV, n2 = BIGV;          // pipelined shfl results
    float mb1[4], mb2[4];
#pragma unroll
    for (int q = 0; q < 4; ++q) { mb1[q] = BIGV; mb2[q] = BIGV; }

    float4 ld[4][2];
#pragma unroll
    for (int x = 0; x < 4; ++x) {        // prologue loads for j=0..3
        int pc = min(max(x - t, 0), NP - 1);
        const float* a = bp + (size_t)pc * (2 * N);
        gload4(ld[x][0], a);
        gload4(ld[x][1], a + N);
    }

    for (int jb = 0; jb < ITER; jb += 4) {
#pragma unroll
        for (int u = 0; u < 4; ++u) {
            const int p = jb + u - t;
            const bool active = (unsigned)p < (unsigned)NP;

            // mailbox group read (consumers; p%4==0 exactly at u==0)
            if (u == 0 && isCons && active) {
                const int gq = p >> 2;
                volatile int* sp = &seqv[w - 1];
                int sv; do { sv = *sp; } while (sv < gq);
                asm volatile("s_waitcnt lgkmcnt(0)" ::: "memory");
                const float* pp = &pay[w - 1][gq][0][0];
#pragma unroll
                for (int q = 0; q < 4; ++q) { mb1[q] = pp[2*q]; mb2[q] = pp[2*q+1]; }
            }

            float e1 = n1, e2 = n2;
            if (isCons) { e1 = mb1[u]; e2 = mb2[u]; }
            if (t == 0) { e1 = BIGV; e2 = BIGV; }

            // D pair landed (issued 4 iterations ago)
            asm volatile("s_waitcnt vmcnt(6)" ::: "memory");
            __builtin_amdgcn_sched_barrier(0);
            const float4 dA = ld[u][0];   // row 2p+1 distances
            const float4 dB = ld[u][1];   // row 2p+2 distances

            // ---------- u-pass (exp2-free recursion) ----------
            float mn1[4], mn2[4], r1u[4], r2u[4];
            mn1[0] = fmin3(lu,     puU[0], e1);     r1u[0] = fmaf(dA.x, LOG2E, mn1[0]);
            mn1[1] = fmin3(puU[0], puU[1], r1u[0]); r1u[1] = fmaf(dA.y, LOG2E, mn1[1]);
            mn1[2] = fmin3(puU[1], puU[2], r1u[1]); r1u[2] = fmaf(dA.z, LOG2E, mn1[2]);
            mn1[3] = fmin3(puU[2], puU[3], r1u[2]); r1u[3] = fmaf(dA.w, LOG2E, mn1[3]);
            mn2[0] = fmin3(e1,     r1u[0], e2);     r2u[0] = fmaf(dB.x, LOG2E, mn2[0]);
            mn2[1] = fmin3(r1u[0], r1u[1], r2u[0]); r2u[1] = fmaf(dB.y, LOG2E, mn2[1]);
            mn2[2] = fmin3(r1u[1], r1u[2], r2u[1]); r2u[2] = fmaf(dB.z, LOG2E, mn2[2]);
            mn2[3] = fmin3(r1u[2], r1u[3], r2u[2]); r2u[3] = fmaf(dB.w, LOG2E, mn2[3]);

            // ---------- exp2-pass (24 independent) ----------
            float ea1[4], eb1[4], ec1[4], ea2[4], eb2[4], ec2[4];
            ea1[0] = fexp2(mn1[0] - lu);     eb1[0] = fexp2(mn1[0] - puU[0]); ec1[0] = fexp2(mn1[0] - e1);
            ea1[1] = fexp2(mn1[1] - puU[0]); eb1[1] = fexp2(mn1[1] - puU[1]); ec1[1] = fexp2(mn1[1] - r1u[0]);
            ea1[2] = fexp2(mn1[2] - puU[1]); eb1[2] = fexp2(mn1[2] - puU[2]); ec1[2] = fexp2(mn1[2] - r1u[1]);
            ea1[3] = fexp2(mn1[3] - puU[2]); eb1[3] = fexp2(mn1[3] - puU[3]); ec1[3] = fexp2(mn1[3] - r1u[2]);
            ea2[0] = fexp2(mn2[0] - e1);     eb2[0] = fexp2(mn2[0] - r1u[0]); ec2[0] = fexp2(mn2[0] - e2);
            ea2[1] = fexp2(mn2[1] - r1u[0]); eb2[1] = fexp2(mn2[1] - r1u[1]); ec2[1] = fexp2(mn2[1] - r2u[0]);
            ea2[2] = fexp2(mn2[2] - r1u[1]); eb2[2] = fexp2(mn2[2] - r1u[2]); ec2[2] = fexp2(mn2[2] - r2u[1]);
            ea2[3] = fexp2(mn2[3] - r1u[2]); eb2[3] = fexp2(mn2[3] - r1u[3]); ec2[3] = fexp2(mn2[3] - r2u[2]);

            // ---------- sigma-pass (boundary s==1 folded) ----------
            float r1s[4], r2s[4];
            r1s[0] = fmaf(puS[0], eb1[0], ea1[0] + ec1[0]);                    // as=1(lu), cs=1(e1)
            r1s[1] = fmaf(puS[0], ea1[1], fmaf(puS[1], eb1[1], r1s[0]*ec1[1]));
            r1s[2] = fmaf(puS[1], ea1[2], fmaf(puS[2], eb1[2], r1s[1]*ec1[2]));
            r1s[3] = fmaf(puS[2], ea1[3], fmaf(puS[3], eb1[3], r1s[2]*ec1[3]));
            r2s[0] = fmaf(r1s[0], eb2[0], ea2[0] + ec2[0]);                    // as=1(e1), cs=1(e2)
            r2s[1] = fmaf(r1s[0], ea2[1], fmaf(r1s[1], eb2[1], r2s[0]*ec2[1]));
            r2s[2] = fmaf(r1s[1], ea2[2], fmaf(r1s[2], eb2[2], r2s[1]*ec2[2]));
            r2s[3] = fmaf(r1s[2], ea2[3], fmaf(r1s[3], eb2[3], r2s[2]*ec2[3]));

            if (active) {                  // masked commit
#pragma unroll
                for (int m = 0; m < KC; ++m) { puU[m] = r2u[m]; puS[m] = r2s[m]; }
                lu  = e2;                                  // normalized
                ex1 = r1u[3] - flog2(r1s[3]);              // normalized edges
                ex2 = r2u[3] - flog2(r2s[3]);
            }

            // producer: payload each pair; seq bump at group end (u==2)
            if (isProd && active) {
                volatile float* pp = &pay[w][p >> 2][p & 3][0];
                pp[0] = ex1; pp[1] = ex2;
            }
            if (u == 2 && isProd && active) {
                asm volatile("s_waitcnt lgkmcnt(0)" ::: "memory");
                *(volatile int*)&seqv[w] = (p >> 2);
            }

            // issue D loads for iteration j+4
            {
                int pc = min(max(p + 4, 0), NP - 1);
                const float* a = bp + (size_t)pc * (2 * N);
                gload4(ld[u][0], a);
                gload4(ld[u][1], a + N);
            }

            // renorm pu every 4 iterations (value-preserving; safe if inactive)
            if (u == 3) {
#pragma unroll
                for (int m = 0; m < KC; ++m) { puU[m] -= flog2(puS[m]); puS[m] = 1.0f; }
            }

            // pipelined handoff for NEXT iteration
            n1 = __shfl_up(ex1, 1);
            n2 = __shfl_up(ex2, 1);
        }
    }

    // R[N][N] = thread 255's puU[3] (puS renormed to 1 at final u==3)
    if (t == TPB - 1) out[b] = puU[KC - 1] * LN2;
}

extern "C" void kernel_launch(void* const* d_in, const int* in_sizes, int n_in,
                              void* d_out, int out_size, void* d_ws, size_t ws_size,
                              hipStream_t stream) {
    const float* D = (const float*)d_in[0];
    float* out = (float*)d_out;
    const int B = in_sizes[0] / (N * N);
    softdtw_kernel<<<B, TPB, 0, stream>>>(D, out);
}

// Round 14
// 349.149 us; speedup vs baseline: 1.9957x; 1.0527x over previous
//
#include <hip/hip_runtime.h>

// Soft-DTW, gamma=1.0, B=64, N=M=1024, barrier-free, LINEAR-WEIGHT cells.
// Identity: with W[i][j] = 2^(kf - v[i][j]) (v = cost in log2 domain),
//   W[i][j] = e^(-d) * (W[i-1][j] + W[i-1][j-1] + W[i][j-1])
// so each cell is add+add+mul; the only per-cell transcendental is
// f = exp2(-d*log2e), which depends ONLY on D -> computed one iteration
// ahead from the load ring, off the dependency chain. Per-thread scale kf
// renormalized once per quad by rcp(W33); the export log2 IS the renorm.
// R14 fix: anchor kf at each thread's FIRST active quad (p==0) to the first
// incoming edge value ev0 (kf=0 for t==0). R13 anchored kf=0 for all threads,
// so first-quad imports 2^(0 - ~150) flushed to zero -> log2(0) -> inf -> NaN.
//
// Skeleton = proven R11/R12: thread t owns cols 4t..4t+3 (0-based), sweeps
// quads of 4 rows; quad p at iteration j = p + t; ITER=512. Handoff t-1 -> t:
// 4x __shfl_up of v-form right edges (pipelined, end of iter). Wave
// boundaries (3): LDS mailbox, groups of 4 quads, seq counter + lgkm fence.
// D: asm global_load_dwordx4 ring, 4 rows/iter, depth 4, counted vmcnt(8).

#define BIGV 1.0e10f
#define LOG2E 1.4426950408889634f
#define LN2  0.6931471805599453f

constexpr int N = 1024;
constexpr int TPB = 256;
constexpr int KC = 4;                // columns per thread
constexpr int RQ = 4;                // rows per iteration (quad)
constexpr int NQ = N / RQ;           // 256 quads
constexpr int NG = NQ / 4;           // 64 groups of 4 quads
constexpr int ITER = 512;            // last real iteration: 255 + 255 = 510

__device__ __forceinline__ float fexp2(float x){float r;asm("v_exp_f32 %0, %1":"=v"(r):"v"(x));return r;}
__device__ __forceinline__ float flog2(float x){float r;asm("v_log_f32 %0, %1":"=v"(r):"v"(x));return r;}
__device__ __forceinline__ float frcp(float x){float r;asm("v_rcp_f32 %0, %1":"=v"(r):"v"(x));return r;}
__device__ __forceinline__ void gload4(float4& d, const float* p){
    asm volatile("global_load_dwordx4 %0, %1, off" : "=v"(d) : "v"(p));
}

__global__ __launch_bounds__(TPB, 1)
void softdtw_kernel(const float* __restrict__ D, float* __restrict__ out){
    const int b = blockIdx.x;
    const int t = threadIdx.x;
    const int lane = t & 63;
    const int w = t >> 6;
    const float* __restrict__ bp = D + (size_t)b * N * N + t * KC;

    __shared__ float pay[3][NG][4][4];   // [boundary][group][quad][row] v-form
    __shared__ int seqv[3];
    if (t < 3) seqv[t] = -1;
    __syncthreads();   // once, before the pipeline

    const bool isProd = (lane == 63) && (w < 3);
    const bool isCons = (lane == 0) && (w > 0);

    float pW[KC] = {0.0f, 0.0f, 0.0f, 0.0f};   // row-above weights (my scale)
    float kf = 0.0f;                            // my scale: W = 2^(kf - v)
    float luW = (t == 0) ? 1.0f : 0.0f;         // diagonal for row0/col0
    float ex[RQ]  = {BIGV, BIGV, BIGV, BIGV};   // my exported right edges (v)
    float nv[RQ]  = {BIGV, BIGV, BIGV, BIGV};   // shfl'd neighbor edges (v)
    float mbv[4][4];
#pragma unroll
    for (int q = 0; q < 4; ++q)
#pragma unroll
        for (int r = 0; r < 4; ++r) mbv[q][r] = BIGV;

    float4 ld[4][4];                   // [slot][row]
#pragma unroll
    for (int x = 0; x < 4; ++x) {      // prologue loads for j=0..3
        int pc = min(max(x - t, 0), NQ - 1);
        const float* a = bp + (size_t)(pc * RQ) * N;
#pragma unroll
        for (int r = 0; r < RQ; ++r) gload4(ld[x][r], a + (size_t)r * N);
    }
    asm volatile("s_waitcnt vmcnt(12)" ::: "memory");
    __builtin_amdgcn_sched_barrier(0);

    float fP[2][16];                   // f ping-pong: f for iter j in fP[j&1]
#pragma unroll
    for (int r = 0; r < RQ; ++r) {
        const float4 dv = ld[0][r];
        fP[0][r*4+0] = fexp2(-LOG2E * dv.x);
        fP[0][r*4+1] = fexp2(-LOG2E * dv.y);
        fP[0][r*4+2] = fexp2(-LOG2E * dv.z);
        fP[0][r*4+3] = fexp2(-LOG2E * dv.w);
    }

    for (int jb = 0; jb < ITER; jb += 4) {
#pragma unroll
        for (int u = 0; u < 4; ++u) {
            const int p = jb + u - t;
            const bool active = (unsigned)p < (unsigned)NQ;

            // mailbox group read (consumers; p%4==0 exactly at u==0)
            if (u == 0 && isCons && active) {
                const int gq = p >> 2;
                volatile int* sp = &seqv[w - 1];
                int sv; do { sv = *sp; } while (sv < gq);
                asm volatile("s_waitcnt lgkmcnt(0)" ::: "memory");
                const float* pp = &pay[w - 1][gq][0][0];
#pragma unroll
                for (int q = 0; q < 16; ++q) (&mbv[0][0])[q] = pp[q];
            }

            // incoming left-edge v's
            float ev0 = nv[0], ev1 = nv[1], ev2 = nv[2], ev3 = nv[3];
            if (isCons) { ev0 = mbv[u][0]; ev1 = mbv[u][1]; ev2 = mbv[u][2]; ev3 = mbv[u][3]; }
            if (t == 0) { ev0 = BIGV; ev1 = BIGV; ev2 = BIGV; ev3 = BIGV; }

            // R14 FIX: anchor my scale to the incoming edge at my first quad
            if (p == 0) kf = (t == 0) ? 0.0f : ev0;

            // slots for iters j and j+1 have landed
            asm volatile("s_waitcnt vmcnt(8)" ::: "memory");
            __builtin_amdgcn_sched_barrier(0);

            // f for NEXT iteration from slot (u+1)&3 (off the chain)
#pragma unroll
            for (int r = 0; r < RQ; ++r) {
                const float4 dv = ld[(u + 1) & 3][r];
                fP[(u+1)&1][r*4+0] = fexp2(-LOG2E * dv.x);
                fP[(u+1)&1][r*4+1] = fexp2(-LOG2E * dv.y);
                fP[(u+1)&1][r*4+2] = fexp2(-LOG2E * dv.z);
                fP[(u+1)&1][r*4+3] = fexp2(-LOG2E * dv.w);
            }

            // import edges to my scale
            float eW0 = fexp2(kf - ev0);
            float eW1 = fexp2(kf - ev1);
            float eW2 = fexp2(kf - ev2);
            float eW3 = fexp2(kf - ev3);

            // ---- 16 cells: W = f*(up + diag + left), row-major ----
            const float* f = fP[u & 1];
            float a0 = pW[0], a1 = pW[1], a2 = pW[2], a3 = pW[3];
            float exv[RQ];
            float dgr = luW;
            {
                float eWr[4] = {eW0, eW1, eW2, eW3};
#pragma unroll
                for (int r = 0; r < RQ; ++r) {
                    float t0 = dgr + eWr[r];
                    float W0 = f[r*4+0] * (a0 + t0);
                    float W1 = f[r*4+1] * ((a1 + a0) + W0);
                    float W2 = f[r*4+2] * ((a2 + a1) + W1);
                    float W3 = f[r*4+3] * ((a3 + a2) + W2);
                    exv[r] = kf - flog2(W3);
                    dgr = eWr[r];
                    a0 = W0; a1 = W1; a2 = W2; a3 = W3;
                }
            }
            float rw = frcp(a3);

            if (active) {                  // masked commit
                pW[0] = a0 * rw; pW[1] = a1 * rw; pW[2] = a2 * rw; pW[3] = 1.0f;
                luW = eW3 * rw;
                kf = exv[3];
                ex[0] = exv[0]; ex[1] = exv[1]; ex[2] = exv[2]; ex[3] = exv[3];
            }

            // producer: payload each quad; seq bump at group end (u==2)
            if (isProd && active) {
                volatile float* pp = &pay[w][p >> 2][p & 3][0];
                pp[0] = ex[0]; pp[1] = ex[1]; pp[2] = ex[2]; pp[3] = ex[3];
            }
            if (u == 2 && isProd && active) {
                asm volatile("s_waitcnt lgkmcnt(0)" ::: "memory");
                *(volatile int*)&seqv[w] = (p >> 2);
            }

            // issue D loads for iteration j+4 into slot u
            {
                int pc = min(max(p + 4, 0), NQ - 1);
                const float* a = bp + (size_t)(pc * RQ) * N;
#pragma unroll
                for (int r = 0; r < RQ; ++r) gload4(ld[u][r], a + (size_t)r * N);
            }

            // pipelined handoff for NEXT iteration
            nv[0] = __shfl_up(ex[0], 1);
            nv[1] = __shfl_up(ex[1], 1);
            nv[2] = __shfl_up(ex[2], 1);
            nv[3] = __shfl_up(ex[3], 1);
        }
    }

    // v[1024][1024] = thread 255's kf (set by its last quad's renorm)
    if (t == TPB - 1) out[b] = kf * LN2;
}

extern "C" void kernel_launch(void* const* d_in, const int* in_sizes, int n_in,
                              void* d_out, int out_size, void* d_ws, size_t ws_size,
                              hipStream_t stream) {
    const float* D = (const float*)d_in[0];
    float* out = (float*)d_out;
    const int B = in_sizes[0] / (N * N);
    softdtw_kernel<<<B, TPB, 0, stream>>>(D, out);
}